// Round 2
// baseline (1261.888 us; speedup 1.0000x reference)
//
#include <hip/hip_runtime.h>
#include <math.h>

#define EPSF 1e-15f
#define MAX_ATANH (1.0f - 1e-5f)
#define ATT 16

__device__ __forceinline__ float geluf(float x) {
    // exact GELU: x * 0.5 * (1 + erf(x / sqrt(2)))
    return 0.5f * x * (1.0f + erff(x * 0.70710678118654752f));
}

// Per-edge: gather endpoints, hyperbolic log-map, MLP score, exp, atomic scatter.
// One thread per edge; accumulators packed per-node in a float4 (one 64B-line RMW
// locality per edge instead of 3 distinct lines).
__global__ void __launch_bounds__(256) edge_pass(
                          const float2* __restrict__ x,
                          const float* __restrict__ W1,   // [2][16]
                          const float* __restrict__ b1,   // [16]
                          const float* __restrict__ W2,   // [16]
                          const int* __restrict__ row,
                          const int* __restrict__ col,
                          float4* __restrict__ acc,       // [V] {den, mx, my, pad}
                          int E) {
    const int e = blockIdx.x * blockDim.x + threadIdx.x;
    if (e >= E) return;

    const int r = row[e];
    const int c = col[e];
    const float2 xi = x[r];
    const float2 xj = x[c];

    // sub = mobius_add(-xi, xj), c = 1
    const float ax = -xi.x, ay = -xi.y;
    const float bx = xj.x,  by = xj.y;
    const float a2 = ax * ax + ay * ay;
    const float b2 = bx * bx + by * by;
    const float ab = ax * bx + ay * by;
    const float ca = 1.0f + 2.0f * ab + b2;   // coef on a
    const float cb = 1.0f - a2;               // coef on b
    const float dn = fmaxf(1.0f + 2.0f * ab + a2 * b2, EPSF);
    const float subx = (ca * ax + cb * bx) / dn;
    const float suby = (ca * ay + cb * by) / dn;

    // log map: v = (2/lam) * atanh(min(n, MAX)) * sub / n ; 2/lam = max(1-|xi|^2, EPS)
    const float n = fmaxf(sqrtf(subx * subx + suby * suby), EPSF);
    const float M = fmaxf(1.0f - (xi.x * xi.x + xi.y * xi.y), EPSF);
    const float scl = M * atanhf(fminf(n, MAX_ATANH)) / n;
    const float vx = scl * subx;
    const float vy = scl * suby;

    // MLP scorer: gelu(v @ W1 + b1) @ W2
    float s = 0.0f;
    #pragma unroll
    for (int k = 0; k < ATT; ++k) {
        const float hk = geluf(fmaf(vx, W1[k], fmaf(vy, W1[ATT + k], b1[k])));
        s = fmaf(hk, W2[k], s);
    }

    // max-free softmax numerator (|s| << 88, exp is safe in f32)
    const float ee = expf(s);
    float* a4 = (float*)&acc[r];
    atomicAdd(a4 + 0, ee);
    atomicAdd(a4 + 1, ee * vx);
    atomicAdd(a4 + 2, ee * vy);
}

// Per-node: normalize, depth mixer (scale+rotation), exp-map update.
__global__ void __launch_bounds__(256) node_pass(
                          const float2* __restrict__ x,
                          const float4* __restrict__ acc,
                          const int* __restrict__ depth,
                          const float* __restrict__ depth_scale,
                          const float* __restrict__ depth_theta,
                          const float* __restrict__ eta_p,
                          float2* __restrict__ out,
                          int V) {
    const float eta = eta_p[0];
    const int stride = gridDim.x * blockDim.x;
    for (int v = blockIdx.x * blockDim.x + threadIdx.x; v < V; v += stride) {
        const float4 a = acc[v];
        const float dv = fmaxf(a.x, EPSF);
        const float mx = a.y / dv;
        const float my = a.z / dv;

        const int d = min(depth[v], 511);
        const float k   = depth_scale[d];
        const float ang = depth_theta[d];
        const float cs = cosf(ang), sn = sinf(ang);
        const float m0 = eta * (k * (cs * mx - sn * my));
        const float m1 = eta * (k * (sn * mx + cs * my));

        const float2 xi = x[v];

        // exp_map_x(xi, m): n, lam, tanh(0.5*lam*n) * m/n
        const float n = fmaxf(sqrtf(m0 * m0 + m1 * m1), EPSF);
        const float M = fmaxf(1.0f - (xi.x * xi.x + xi.y * xi.y), EPSF);
        const float t = tanhf(n / M);          // 0.5 * lam * n = n / M
        const float bx = t * m0 / n;
        const float by = t * m1 / n;

        // mobius_add(xi, b)
        const float a2 = xi.x * xi.x + xi.y * xi.y;
        const float b2 = bx * bx + by * by;
        const float ab = xi.x * bx + xi.y * by;
        const float ca = 1.0f + 2.0f * ab + b2;
        const float cb = 1.0f - a2;
        const float dn = fmaxf(1.0f + 2.0f * ab + a2 * b2, EPSF);

        out[v] = make_float2((ca * xi.x + cb * bx) / dn,
                             (ca * xi.y + cb * by) / dn);
    }
}

extern "C" void kernel_launch(void* const* d_in, const int* in_sizes, int n_in,
                              void* d_out, int out_size, void* d_ws, size_t ws_size,
                              hipStream_t stream) {
    const float2* x          = (const float2*)d_in[0];
    const float*  W1         = (const float*)d_in[1];
    const float*  b1         = (const float*)d_in[2];
    const float*  W2         = (const float*)d_in[3];
    const float*  eta        = (const float*)d_in[4];
    const float*  dscale     = (const float*)d_in[5];
    const float*  dtheta     = (const float*)d_in[6];
    const int*    edge_index = (const int*)d_in[7];
    const int*    depth      = (const int*)d_in[8];

    const int V = in_sizes[0] / 2;
    const int E = in_sizes[7] / 2;

    const int* row = edge_index;
    const int* col = edge_index + E;

    float4* acc = (float4*)d_ws;

    // zero the accumulators (harness does not re-poison between replays)
    hipMemsetAsync(d_ws, 0, (size_t)V * sizeof(float4), stream);

    const int block = 256;
    const int gridE = (E + block - 1) / block;   // one thread per edge
    const int gridV = min((V + block - 1) / block, 4096);

    edge_pass<<<gridE, block, 0, stream>>>(x, W1, b1, W2, row, col, acc, E);
    node_pass<<<gridV, block, 0, stream>>>(x, acc, depth, dscale, dtheta, eta,
                                           (float2*)d_out, V);
}

// Round 3
// 303.323 us; speedup vs baseline: 4.1602x; 4.1602x over previous
//
#include <hip/hip_runtime.h>
#include <math.h>

#define EPSF 1e-15f
#define MAX_ATANH (1.0f - 1e-5f)
#define ATT 16

#define LOG_NPB 11                 // nodes per bucket = 2048
#define NPB (1 << LOG_NPB)
#define MAXB 1024                  // max buckets (V <= 2^21)
#define NBLK 1024                  // blocks in hist/scatter kernels

// ---------------- K1: per-block bucket histogram (LDS atomics only) --------
__global__ void __launch_bounds__(256) hist_kernel(const int* __restrict__ row,
                                                   int E, int B,
                                                   unsigned* __restrict__ counts /*[B][NBLK]*/) {
    __shared__ unsigned h[MAXB];
    for (int i = threadIdx.x; i < B; i += 256) h[i] = 0u;
    __syncthreads();
    const int T = gridDim.x * 256;
    for (int e = blockIdx.x * 256 + threadIdx.x; e < E; e += T)
        atomicAdd(&h[((unsigned)row[e]) >> LOG_NPB], 1u);
    __syncthreads();
    for (int i = threadIdx.x; i < B; i += 256)
        counts[(size_t)i * gridDim.x + blockIdx.x] = h[i];
}

// ---------------- K2a: exclusive scan of each bucket's NBLK counts ---------
__global__ void __launch_bounds__(256) scan_blocks_kernel(const unsigned* __restrict__ counts,
                                                          unsigned* __restrict__ within,
                                                          unsigned* __restrict__ totals,
                                                          int nblk) {
    const int b = blockIdx.x;
    const unsigned* src = counts + (size_t)b * nblk;
    unsigned* dst = within + (size_t)b * nblk;
    __shared__ unsigned s[256];
    const int ipt = (nblk + 255) / 256;        // 4
    unsigned vals[8];
    unsigned sum = 0u;
    for (int k = 0; k < ipt; ++k) {
        int idx = threadIdx.x * ipt + k;
        vals[k] = (idx < nblk) ? src[idx] : 0u;
        sum += vals[k];
    }
    s[threadIdx.x] = sum;
    __syncthreads();
    for (int off = 1; off < 256; off <<= 1) {
        unsigned t = (threadIdx.x >= off) ? s[threadIdx.x - off] : 0u;
        __syncthreads();
        s[threadIdx.x] += t;
        __syncthreads();
    }
    unsigned base = (threadIdx.x > 0) ? s[threadIdx.x - 1] : 0u;
    for (int k = 0; k < ipt; ++k) {
        int idx = threadIdx.x * ipt + k;
        if (idx < nblk) { dst[idx] = base; base += vals[k]; }
    }
    if (threadIdx.x == 255) totals[b] = s[255];
}

// ---------------- K2b: exclusive scan of bucket totals -> base[B+1] --------
__global__ void __launch_bounds__(256) scan_totals_kernel(const unsigned* __restrict__ totals,
                                                          unsigned* __restrict__ base, int B) {
    __shared__ unsigned s[256];
    const int ipt = (B + 255) / 256;           // 4
    unsigned vals[8];
    unsigned sum = 0u;
    for (int k = 0; k < ipt; ++k) {
        int idx = threadIdx.x * ipt + k;
        vals[k] = (idx < B) ? totals[idx] : 0u;
        sum += vals[k];
    }
    s[threadIdx.x] = sum;
    __syncthreads();
    for (int off = 1; off < 256; off <<= 1) {
        unsigned t = (threadIdx.x >= off) ? s[threadIdx.x - off] : 0u;
        __syncthreads();
        s[threadIdx.x] += t;
        __syncthreads();
    }
    unsigned b0 = (threadIdx.x > 0) ? s[threadIdx.x - 1] : 0u;
    for (int k = 0; k < ipt; ++k) {
        int idx = threadIdx.x * ipt + k;
        if (idx < B) { base[idx] = b0; b0 += vals[k]; }
    }
    if (threadIdx.x == 255) base[B] = s[255];
}

// ---------------- K3: scatter edges into bucket-sorted payload -------------
// payload word: (lrow:11 << 21) | col:21   (V <= 2^21)
__global__ void __launch_bounds__(256) scatter_kernel(const int* __restrict__ row,
                                                      const int* __restrict__ col,
                                                      int E, int B,
                                                      const unsigned* __restrict__ base,
                                                      const unsigned* __restrict__ within,
                                                      unsigned* __restrict__ payload) {
    __shared__ unsigned cur[MAXB];
    const int nblk = gridDim.x;
    for (int i = threadIdx.x; i < B; i += 256)
        cur[i] = base[i] + within[(size_t)i * nblk + blockIdx.x];
    __syncthreads();
    const int T = nblk * 256;
    for (int e = blockIdx.x * 256 + threadIdx.x; e < E; e += T) {
        const unsigned r = (unsigned)row[e];
        const unsigned b = r >> LOG_NPB;
        const unsigned pos = atomicAdd(&cur[b], 1u);
        payload[pos] = ((r & (NPB - 1)) << 21) | (unsigned)col[e];
    }
}

// ---------------- K4: per-bucket LDS accumulate + node epilogue ------------
__global__ void __launch_bounds__(1024) bucket_reduce_kernel(
        const float2* __restrict__ x,
        const float* __restrict__ W1,   // [2][16]
        const float* __restrict__ b1,   // [16]
        const float* __restrict__ W2,   // [16]
        const unsigned* __restrict__ base,
        const unsigned* __restrict__ payload,
        const int* __restrict__ depth,
        const float* __restrict__ depth_scale,
        const float* __restrict__ depth_theta,
        const float* __restrict__ eta_p,
        float2* __restrict__ out, int V) {
    __shared__ float sden[NPB];
    __shared__ float smx[NPB];
    __shared__ float smy[NPB];
    const int b = blockIdx.x;
    const int nodeBase = b << LOG_NPB;
    for (int i = threadIdx.x; i < NPB; i += blockDim.x) {
        sden[i] = 0.f; smx[i] = 0.f; smy[i] = 0.f;
    }
    __syncthreads();

    const unsigned e0 = base[b], e1 = base[b + 1];
    for (unsigned e = e0 + threadIdx.x; e < e1; e += blockDim.x) {
        const unsigned p = payload[e];
        const unsigned lrow = p >> 21;
        const unsigned c = p & 0x1FFFFFu;
        const float2 xi = x[nodeBase + (int)lrow];   // 16KB window, L1-hot
        const float2 xj = x[c];                      // random, L2/LLC

        // sub = mobius_add(-xi, xj), curvature 1
        const float ax = -xi.x, ay = -xi.y;
        const float bx = xj.x,  by = xj.y;
        const float a2 = ax * ax + ay * ay;
        const float b2 = bx * bx + by * by;
        const float ab = ax * bx + ay * by;
        const float ca = 1.0f + 2.0f * ab + b2;
        const float cb = 1.0f - a2;
        const float dn = fmaxf(1.0f + 2.0f * ab + a2 * b2, EPSF);
        const float subx = (ca * ax + cb * bx) / dn;
        const float suby = (ca * ay + cb * by) / dn;

        // log map
        const float n = fmaxf(sqrtf(subx * subx + suby * suby), EPSF);
        const float M = fmaxf(1.0f - (xi.x * xi.x + xi.y * xi.y), EPSF);
        const float scl = M * atanhf(fminf(n, MAX_ATANH)) / n;
        const float vx = scl * subx;
        const float vy = scl * suby;

        // MLP scorer: gelu(v @ W1 + b1) @ W2  (exact GELU)
        float s = 0.0f;
        #pragma unroll
        for (int k = 0; k < ATT; ++k) {
            const float u = fmaf(vx, W1[k], fmaf(vy, W1[ATT + k], b1[k]));
            const float hk = 0.5f * u * (1.0f + erff(u * 0.70710678118654752f));
            s = fmaf(hk, W2[k], s);
        }

        // max-free softmax numerator (f32 exp range is ample here)
        const float ee = expf(s);
        atomicAdd(&sden[lrow], ee);        // ds_add_f32 — LDS, cheap
        atomicAdd(&smx[lrow], ee * vx);
        atomicAdd(&smy[lrow], ee * vy);
    }
    __syncthreads();

    // node epilogue: normalize, depth mixer, exp-map
    const float eta = eta_p[0];
    for (int i = threadIdx.x; i < NPB; i += blockDim.x) {
        const int v = nodeBase + i;
        if (v >= V) break;
        const float dv = fmaxf(sden[i], EPSF);
        const float mx = smx[i] / dv;
        const float my = smy[i] / dv;

        const int d = min(depth[v], 511);
        const float k   = depth_scale[d];
        const float ang = depth_theta[d];
        const float cs = cosf(ang), sn = sinf(ang);
        const float m0 = eta * (k * (cs * mx - sn * my));
        const float m1 = eta * (k * (sn * mx + cs * my));

        const float2 xi = x[v];

        const float n = fmaxf(sqrtf(m0 * m0 + m1 * m1), EPSF);
        const float M = fmaxf(1.0f - (xi.x * xi.x + xi.y * xi.y), EPSF);
        const float t = tanhf(n / M);
        const float bx = t * m0 / n;
        const float by = t * m1 / n;

        const float a2 = xi.x * xi.x + xi.y * xi.y;
        const float b2 = bx * bx + by * by;
        const float ab = xi.x * bx + xi.y * by;
        const float ca = 1.0f + 2.0f * ab + b2;
        const float cb = 1.0f - a2;
        const float dn = fmaxf(1.0f + 2.0f * ab + a2 * b2, EPSF);

        out[v] = make_float2((ca * xi.x + cb * bx) / dn,
                             (ca * xi.y + cb * by) / dn);
    }
}

extern "C" void kernel_launch(void* const* d_in, const int* in_sizes, int n_in,
                              void* d_out, int out_size, void* d_ws, size_t ws_size,
                              hipStream_t stream) {
    const float2* x          = (const float2*)d_in[0];
    const float*  W1         = (const float*)d_in[1];
    const float*  b1         = (const float*)d_in[2];
    const float*  W2         = (const float*)d_in[3];
    const float*  eta        = (const float*)d_in[4];
    const float*  dscale     = (const float*)d_in[5];
    const float*  dtheta     = (const float*)d_in[6];
    const int*    edge_index = (const int*)d_in[7];
    const int*    depth      = (const int*)d_in[8];

    const int V = in_sizes[0] / 2;
    const int E = in_sizes[7] / 2;
    const int B = (V + NPB - 1) >> LOG_NPB;       // 1024 for V = 2^21

    const int* row = edge_index;
    const int* col = edge_index + E;

    // workspace layout (all u32): payload[E] | counts[B*NBLK] | within[B*NBLK]
    //                             | totals[B] | base[B+1]
    unsigned* payload = (unsigned*)d_ws;
    unsigned* counts  = payload + E;
    unsigned* within  = counts + (size_t)B * NBLK;
    unsigned* totals  = within + (size_t)B * NBLK;
    unsigned* base    = totals + B;

    hist_kernel<<<NBLK, 256, 0, stream>>>(row, E, B, counts);
    scan_blocks_kernel<<<B, 256, 0, stream>>>(counts, within, totals, NBLK);
    scan_totals_kernel<<<1, 256, 0, stream>>>(totals, base, B);
    scatter_kernel<<<NBLK, 256, 0, stream>>>(row, col, E, B, base, within, payload);
    bucket_reduce_kernel<<<B, 1024, 0, stream>>>(x, W1, b1, W2, base, payload,
                                                 depth, dscale, dtheta, eta,
                                                 (float2*)d_out, V);
}

// Round 4
// 285.644 us; speedup vs baseline: 4.4177x; 1.0619x over previous
//
#include <hip/hip_runtime.h>
#include <math.h>

#define EPSF 1e-15f
#define MAX_ATANH (1.0f - 1e-5f)
#define ATT 16

#define LOG_NPB 11                 // nodes per bucket = 2048
#define NPB (1 << LOG_NPB)
#define MAXB 1024                  // max buckets (V <= 2^21)
#define NBLK 1024                  // blocks in hist/scatter kernels

// ---- fast branch-free transcendentals (threshold headroom ~5x) ------------
__device__ __forceinline__ float fast_gelu(float u) {
    // exact-GELU via A&S 7.1.26 erf approx (abs err <= 1.5e-7), branch-free
    const float x  = fabsf(u) * 0.70710678118654752f;       // |u|/sqrt(2)
    const float w  = __fdividef(1.0f, fmaf(0.3275911f, x, 1.0f));
    float p = 1.061405429f;
    p = fmaf(p, w, -1.453152027f);
    p = fmaf(p, w,  1.421413741f);
    p = fmaf(p, w, -0.284496736f);
    p = fmaf(p, w,  0.254829592f);
    const float e    = __expf(-0.5f * u * u);               // exp(-x^2)
    const float erfp = fmaf(-p * w, e, 1.0f);               // erf(|x|)
    const float er   = copysignf(erfp, u);
    return 0.5f * u * (1.0f + er);
}

__device__ __forceinline__ float fast_atanh(float z) {
    // 0.5*ln((1+z)/(1-z)); z in [0, 1-1e-5]
    return 0.5f * __logf(__fdividef(1.0f + z, 1.0f - z));
}

__device__ __forceinline__ float fast_tanh(float z) {
    // z >= 0 here; tanh(z) = 1 - 2/(exp(2z)+1)
    return 1.0f - __fdividef(2.0f, __expf(2.0f * z) + 1.0f);
}

// ---------------- K1: per-block bucket histogram (LDS atomics only) --------
__global__ void __launch_bounds__(256) hist_kernel(const int* __restrict__ row,
                                                   int E, int B,
                                                   unsigned* __restrict__ counts /*[B][NBLK]*/) {
    __shared__ unsigned h[MAXB];
    for (int i = threadIdx.x; i < B; i += 256) h[i] = 0u;
    __syncthreads();
    const int T = gridDim.x * 256;
    const int nv = E >> 2;
    const int4* row4 = (const int4*)row;
    for (int i = blockIdx.x * 256 + threadIdx.x; i < nv; i += T) {
        const int4 r = row4[i];
        atomicAdd(&h[((unsigned)r.x) >> LOG_NPB], 1u);
        atomicAdd(&h[((unsigned)r.y) >> LOG_NPB], 1u);
        atomicAdd(&h[((unsigned)r.z) >> LOG_NPB], 1u);
        atomicAdd(&h[((unsigned)r.w) >> LOG_NPB], 1u);
    }
    for (int e = (nv << 2) + blockIdx.x * 256 + threadIdx.x; e < E; e += T)
        atomicAdd(&h[((unsigned)row[e]) >> LOG_NPB], 1u);
    __syncthreads();
    for (int i = threadIdx.x; i < B; i += 256)
        counts[(size_t)i * gridDim.x + blockIdx.x] = h[i];
}

// ---------------- K2a: exclusive scan of each bucket's NBLK counts ---------
// NBLK = 1024, 256 threads, exactly 4 elems/thread (compile-time unroll).
__global__ void __launch_bounds__(256) scan_blocks_kernel(const unsigned* __restrict__ counts,
                                                          unsigned* __restrict__ within,
                                                          unsigned* __restrict__ totals) {
    const int b = blockIdx.x;
    const unsigned* src = counts + (size_t)b * NBLK;
    unsigned* dst = within + (size_t)b * NBLK;
    __shared__ unsigned s[256];
    unsigned v0, v1, v2, v3;
    {
        const uint4 v = ((const uint4*)src)[threadIdx.x];
        v0 = v.x; v1 = v.y; v2 = v.z; v3 = v.w;
    }
    s[threadIdx.x] = v0 + v1 + v2 + v3;
    __syncthreads();
    for (int off = 1; off < 256; off <<= 1) {
        unsigned t = (threadIdx.x >= off) ? s[threadIdx.x - off] : 0u;
        __syncthreads();
        s[threadIdx.x] += t;
        __syncthreads();
    }
    unsigned base = (threadIdx.x > 0) ? s[threadIdx.x - 1] : 0u;
    uint4 o;
    o.x = base; o.y = o.x + v0; o.z = o.y + v1; o.w = o.z + v2;
    ((uint4*)dst)[threadIdx.x] = o;
    if (threadIdx.x == 255) totals[b] = s[255];
}

// ---------------- K2b: exclusive scan of bucket totals -> base[B+1] --------
__global__ void __launch_bounds__(256) scan_totals_kernel(const unsigned* __restrict__ totals,
                                                          unsigned* __restrict__ base, int B) {
    __shared__ unsigned s[256];
    unsigned v0 = 0, v1 = 0, v2 = 0, v3 = 0;
    const int i0 = threadIdx.x * 4;
    if (i0 + 3 < B) {
        const uint4 v = ((const uint4*)totals)[threadIdx.x];
        v0 = v.x; v1 = v.y; v2 = v.z; v3 = v.w;
    } else {
        if (i0 + 0 < B) v0 = totals[i0 + 0];
        if (i0 + 1 < B) v1 = totals[i0 + 1];
        if (i0 + 2 < B) v2 = totals[i0 + 2];
        if (i0 + 3 < B) v3 = totals[i0 + 3];
    }
    s[threadIdx.x] = v0 + v1 + v2 + v3;
    __syncthreads();
    for (int off = 1; off < 256; off <<= 1) {
        unsigned t = (threadIdx.x >= off) ? s[threadIdx.x - off] : 0u;
        __syncthreads();
        s[threadIdx.x] += t;
        __syncthreads();
    }
    unsigned b0 = (threadIdx.x > 0) ? s[threadIdx.x - 1] : 0u;
    if (i0 + 0 < B) base[i0 + 0] = b0;           b0 += v0;
    if (i0 + 1 < B) base[i0 + 1] = b0;           b0 += v1;
    if (i0 + 2 < B) base[i0 + 2] = b0;           b0 += v2;
    if (i0 + 3 < B) base[i0 + 3] = b0;           b0 += v3;
    if (threadIdx.x == 255) base[B] = s[255];
}

// ---------------- K3: scatter edges into bucket-sorted payload -------------
// payload word: (lrow:11 << 21) | col:21   (V <= 2^21)
__global__ void __launch_bounds__(256) scatter_kernel(const int* __restrict__ row,
                                                      const int* __restrict__ col,
                                                      int E, int B,
                                                      const unsigned* __restrict__ base,
                                                      const unsigned* __restrict__ within,
                                                      unsigned* __restrict__ payload) {
    __shared__ unsigned cur[MAXB];
    const int nblk = gridDim.x;
    for (int i = threadIdx.x; i < B; i += 256)
        cur[i] = base[i] + within[(size_t)i * nblk + blockIdx.x];
    __syncthreads();
    const int T = nblk * 256;
    const int nv = E >> 2;
    const int4* row4 = (const int4*)row;
    const int4* col4 = (const int4*)col;
    for (int i = blockIdx.x * 256 + threadIdx.x; i < nv; i += T) {
        const int4 r = row4[i];
        const int4 c = col4[i];
        {
            const unsigned rr = (unsigned)r.x;
            const unsigned pos = atomicAdd(&cur[rr >> LOG_NPB], 1u);
            payload[pos] = ((rr & (NPB - 1)) << 21) | (unsigned)c.x;
        }
        {
            const unsigned rr = (unsigned)r.y;
            const unsigned pos = atomicAdd(&cur[rr >> LOG_NPB], 1u);
            payload[pos] = ((rr & (NPB - 1)) << 21) | (unsigned)c.y;
        }
        {
            const unsigned rr = (unsigned)r.z;
            const unsigned pos = atomicAdd(&cur[rr >> LOG_NPB], 1u);
            payload[pos] = ((rr & (NPB - 1)) << 21) | (unsigned)c.z;
        }
        {
            const unsigned rr = (unsigned)r.w;
            const unsigned pos = atomicAdd(&cur[rr >> LOG_NPB], 1u);
            payload[pos] = ((rr & (NPB - 1)) << 21) | (unsigned)c.w;
        }
    }
    for (int e = (nv << 2) + blockIdx.x * 256 + threadIdx.x; e < E; e += T) {
        const unsigned rr = (unsigned)row[e];
        const unsigned pos = atomicAdd(&cur[rr >> LOG_NPB], 1u);
        payload[pos] = ((rr & (NPB - 1)) << 21) | (unsigned)col[e];
    }
}

// ---------------- K4: per-bucket LDS accumulate + node epilogue ------------
__global__ void __launch_bounds__(1024) bucket_reduce_kernel(
        const float2* __restrict__ x,
        const float* __restrict__ W1,   // [2][16]
        const float* __restrict__ b1,   // [16]
        const float* __restrict__ W2,   // [16]
        const unsigned* __restrict__ base,
        const unsigned* __restrict__ payload,
        const int* __restrict__ depth,
        const float* __restrict__ depth_scale,
        const float* __restrict__ depth_theta,
        const float* __restrict__ eta_p,
        float2* __restrict__ out, int V) {
    __shared__ float sden[NPB];
    __shared__ float smx[NPB];
    __shared__ float smy[NPB];
    const int b = blockIdx.x;
    const int nodeBase = b << LOG_NPB;
    for (int i = threadIdx.x; i < NPB; i += blockDim.x) {
        sden[i] = 0.f; smx[i] = 0.f; smy[i] = 0.f;
    }
    __syncthreads();

    const unsigned e0 = base[b], e1 = base[b + 1];
    for (unsigned e = e0 + threadIdx.x; e < e1; e += blockDim.x) {
        const unsigned p = payload[e];
        const unsigned lrow = p >> 21;
        const unsigned c = p & 0x1FFFFFu;
        const float2 xi = x[nodeBase + (int)lrow];   // 16KB window, L1-hot
        const float2 xj = x[c];                      // random, L2/LLC

        // sub = mobius_add(-xi, xj), curvature 1
        const float ax = -xi.x, ay = -xi.y;
        const float bx = xj.x,  by = xj.y;
        const float a2 = ax * ax + ay * ay;
        const float b2 = bx * bx + by * by;
        const float ab = ax * bx + ay * by;
        const float ca = 1.0f + 2.0f * ab + b2;
        const float cb = 1.0f - a2;
        const float dn = fmaxf(1.0f + 2.0f * ab + a2 * b2, EPSF);
        const float rdn = __fdividef(1.0f, dn);
        const float subx = (ca * ax + cb * bx) * rdn;
        const float suby = (ca * ay + cb * by) * rdn;

        // log map
        const float n = fmaxf(sqrtf(subx * subx + suby * suby), EPSF);
        const float M = fmaxf(1.0f - (xi.x * xi.x + xi.y * xi.y), EPSF);
        const float scl = M * fast_atanh(fminf(n, MAX_ATANH)) * __fdividef(1.0f, n);
        const float vx = scl * subx;
        const float vy = scl * suby;

        // MLP scorer: gelu(v @ W1 + b1) @ W2  (exact GELU via fast erf)
        float s = 0.0f;
        #pragma unroll
        for (int k = 0; k < ATT; ++k) {
            const float u = fmaf(vx, W1[k], fmaf(vy, W1[ATT + k], b1[k]));
            s = fmaf(fast_gelu(u), W2[k], s);
        }

        // max-free softmax numerator (f32 exp range is ample here)
        const float ee = __expf(s);
        atomicAdd(&sden[lrow], ee);        // ds_add_f32 — LDS, cheap
        atomicAdd(&smx[lrow], ee * vx);
        atomicAdd(&smy[lrow], ee * vy);
    }
    __syncthreads();

    // node epilogue: normalize, depth mixer, exp-map
    const float eta = eta_p[0];
    for (int i = threadIdx.x; i < NPB; i += blockDim.x) {
        const int v = nodeBase + i;
        if (v >= V) break;
        const float rdv = __fdividef(1.0f, fmaxf(sden[i], EPSF));
        const float mx = smx[i] * rdv;
        const float my = smy[i] * rdv;

        const int d = min(depth[v], 511);
        const float k   = depth_scale[d];
        const float ang = depth_theta[d];
        const float cs = __cosf(ang), sn = __sinf(ang);
        const float m0 = eta * (k * (cs * mx - sn * my));
        const float m1 = eta * (k * (sn * mx + cs * my));

        const float2 xi = x[v];

        const float n = fmaxf(sqrtf(m0 * m0 + m1 * m1), EPSF);
        const float M = fmaxf(1.0f - (xi.x * xi.x + xi.y * xi.y), EPSF);
        const float t = fast_tanh(__fdividef(n, M));
        const float tn = t * __fdividef(1.0f, n);
        const float bx = tn * m0;
        const float by = tn * m1;

        const float a2 = xi.x * xi.x + xi.y * xi.y;
        const float b2 = bx * bx + by * by;
        const float ab = xi.x * bx + xi.y * by;
        const float ca = 1.0f + 2.0f * ab + b2;
        const float cb = 1.0f - a2;
        const float dn = fmaxf(1.0f + 2.0f * ab + a2 * b2, EPSF);
        const float rdn = __fdividef(1.0f, dn);

        out[v] = make_float2((ca * xi.x + cb * bx) * rdn,
                             (ca * xi.y + cb * by) * rdn);
    }
}

extern "C" void kernel_launch(void* const* d_in, const int* in_sizes, int n_in,
                              void* d_out, int out_size, void* d_ws, size_t ws_size,
                              hipStream_t stream) {
    const float2* x          = (const float2*)d_in[0];
    const float*  W1         = (const float*)d_in[1];
    const float*  b1         = (const float*)d_in[2];
    const float*  W2         = (const float*)d_in[3];
    const float*  eta        = (const float*)d_in[4];
    const float*  dscale     = (const float*)d_in[5];
    const float*  dtheta     = (const float*)d_in[6];
    const int*    edge_index = (const int*)d_in[7];
    const int*    depth      = (const int*)d_in[8];

    const int V = in_sizes[0] / 2;
    const int E = in_sizes[7] / 2;
    const int B = (V + NPB - 1) >> LOG_NPB;       // 1024 for V = 2^21

    const int* row = edge_index;
    const int* col = edge_index + E;

    // workspace layout (all u32): payload[E] | counts[B*NBLK] | within[B*NBLK]
    //                             | totals[B] | base[B+1]
    unsigned* payload = (unsigned*)d_ws;
    unsigned* counts  = payload + E;
    unsigned* within  = counts + (size_t)B * NBLK;
    unsigned* totals  = within + (size_t)B * NBLK;
    unsigned* base    = totals + B;

    hist_kernel<<<NBLK, 256, 0, stream>>>(row, E, B, counts);
    scan_blocks_kernel<<<B, 256, 0, stream>>>(counts, within, totals);
    scan_totals_kernel<<<1, 256, 0, stream>>>(totals, base, B);
    scatter_kernel<<<NBLK, 256, 0, stream>>>(row, col, E, B, base, within, payload);
    bucket_reduce_kernel<<<B, 1024, 0, stream>>>(x, W1, b1, W2, base, payload,
                                                 depth, dscale, dtheta, eta,
                                                 (float2*)d_out, V);
}

// Round 5
// 275.368 us; speedup vs baseline: 4.5826x; 1.0373x over previous
//
#include <hip/hip_runtime.h>
#include <math.h>

#define EPSF 1e-15f
#define MAX_ATANH (1.0f - 1e-5f)
#define ATT 16

#define LOG_NPB 10                 // nodes per bucket = 1024
#define NPB (1 << LOG_NPB)
#define MAXB 2048                  // max buckets (V <= 2^21)
#define NBLK 512                   // blocks in hist/scatter kernels

// ---- fast branch-free transcendentals (threshold headroom ~5x) ------------
__device__ __forceinline__ float fast_gelu(float u) {
    // exact-GELU via A&S 7.1.26 erf approx (abs err <= 1.5e-7), branch-free
    const float x  = fabsf(u) * 0.70710678118654752f;       // |u|/sqrt(2)
    const float w  = __fdividef(1.0f, fmaf(0.3275911f, x, 1.0f));
    float p = 1.061405429f;
    p = fmaf(p, w, -1.453152027f);
    p = fmaf(p, w,  1.421413741f);
    p = fmaf(p, w, -0.284496736f);
    p = fmaf(p, w,  0.254829592f);
    const float e    = __expf(-0.5f * u * u);               // exp(-x^2)
    const float erfp = fmaf(-p * w, e, 1.0f);               // erf(|x|)
    const float er   = copysignf(erfp, u);
    return 0.5f * u * (1.0f + er);
}

__device__ __forceinline__ float fast_atanh(float z) {
    // 0.5*ln((1+z)/(1-z)); z in [0, 1-1e-5]
    return 0.5f * __logf(__fdividef(1.0f + z, 1.0f - z));
}

__device__ __forceinline__ float fast_tanh(float z) {
    // z >= 0 here; tanh(z) = 1 - 2/(exp(2z)+1)
    return 1.0f - __fdividef(2.0f, __expf(2.0f * z) + 1.0f);
}

// ---------------- K1: per-block bucket histogram (LDS atomics only) --------
__global__ void __launch_bounds__(256) hist_kernel(const int* __restrict__ row,
                                                   int E, int B,
                                                   unsigned* __restrict__ counts /*[B][NBLK]*/) {
    __shared__ unsigned h[MAXB];
    for (int i = threadIdx.x; i < B; i += 256) h[i] = 0u;
    __syncthreads();
    const int T = gridDim.x * 256;
    const int nv = E >> 2;
    const int4* row4 = (const int4*)row;
    for (int i = blockIdx.x * 256 + threadIdx.x; i < nv; i += T) {
        const int4 r = row4[i];
        atomicAdd(&h[((unsigned)r.x) >> LOG_NPB], 1u);
        atomicAdd(&h[((unsigned)r.y) >> LOG_NPB], 1u);
        atomicAdd(&h[((unsigned)r.z) >> LOG_NPB], 1u);
        atomicAdd(&h[((unsigned)r.w) >> LOG_NPB], 1u);
    }
    for (int e = (nv << 2) + blockIdx.x * 256 + threadIdx.x; e < E; e += T)
        atomicAdd(&h[((unsigned)row[e]) >> LOG_NPB], 1u);
    __syncthreads();
    for (int i = threadIdx.x; i < B; i += 256)
        counts[(size_t)i * gridDim.x + blockIdx.x] = h[i];
}

// ---------------- K2a: exclusive scan of each bucket's NBLK counts ---------
// NBLK = 512, 256 threads, exactly 2 elems/thread.
__global__ void __launch_bounds__(256) scan_blocks_kernel(const unsigned* __restrict__ counts,
                                                          unsigned* __restrict__ within,
                                                          unsigned* __restrict__ totals) {
    const int b = blockIdx.x;
    const unsigned* src = counts + (size_t)b * NBLK;
    unsigned* dst = within + (size_t)b * NBLK;
    __shared__ unsigned s[256];
    unsigned v0, v1;
    {
        const uint2 v = ((const uint2*)src)[threadIdx.x];
        v0 = v.x; v1 = v.y;
    }
    s[threadIdx.x] = v0 + v1;
    __syncthreads();
    for (int off = 1; off < 256; off <<= 1) {
        unsigned t = (threadIdx.x >= off) ? s[threadIdx.x - off] : 0u;
        __syncthreads();
        s[threadIdx.x] += t;
        __syncthreads();
    }
    unsigned base = (threadIdx.x > 0) ? s[threadIdx.x - 1] : 0u;
    uint2 o;
    o.x = base; o.y = base + v0;
    ((uint2*)dst)[threadIdx.x] = o;
    if (threadIdx.x == 255) totals[b] = s[255];
}

// ---------------- K2b: exclusive scan of bucket totals -> base[B+1] --------
// B <= 2048; 256 threads, 8 elems/thread, static unroll.
__global__ void __launch_bounds__(256) scan_totals_kernel(const unsigned* __restrict__ totals,
                                                          unsigned* __restrict__ base, int B) {
    __shared__ unsigned s[256];
    unsigned vals[8];
    const int i0 = threadIdx.x * 8;
    unsigned sum = 0u;
    #pragma unroll
    for (int k = 0; k < 8; ++k) {
        vals[k] = (i0 + k < B) ? totals[i0 + k] : 0u;
        sum += vals[k];
    }
    s[threadIdx.x] = sum;
    __syncthreads();
    for (int off = 1; off < 256; off <<= 1) {
        unsigned t = (threadIdx.x >= off) ? s[threadIdx.x - off] : 0u;
        __syncthreads();
        s[threadIdx.x] += t;
        __syncthreads();
    }
    unsigned b0 = (threadIdx.x > 0) ? s[threadIdx.x - 1] : 0u;
    #pragma unroll
    for (int k = 0; k < 8; ++k) {
        if (i0 + k < B) base[i0 + k] = b0;
        b0 += vals[k];
    }
    if (threadIdx.x == 255) base[B] = s[255];
}

// ---------------- K3: scatter edges into bucket-sorted payload -------------
// payload word: (lrow:10 << 21) | col:21   (V <= 2^21)
__global__ void __launch_bounds__(256) scatter_kernel(const int* __restrict__ row,
                                                      const int* __restrict__ col,
                                                      int E, int B,
                                                      const unsigned* __restrict__ base,
                                                      const unsigned* __restrict__ within,
                                                      unsigned* __restrict__ payload) {
    __shared__ unsigned cur[MAXB];
    const int nblk = gridDim.x;
    for (int i = threadIdx.x; i < B; i += 256)
        cur[i] = base[i] + within[(size_t)i * nblk + blockIdx.x];
    __syncthreads();
    const int T = nblk * 256;
    const int nv = E >> 2;
    const int4* row4 = (const int4*)row;
    const int4* col4 = (const int4*)col;
    for (int i = blockIdx.x * 256 + threadIdx.x; i < nv; i += T) {
        const int4 r = row4[i];
        const int4 c = col4[i];
        {
            const unsigned rr = (unsigned)r.x;
            const unsigned pos = atomicAdd(&cur[rr >> LOG_NPB], 1u);
            payload[pos] = ((rr & (NPB - 1)) << 21) | (unsigned)c.x;
        }
        {
            const unsigned rr = (unsigned)r.y;
            const unsigned pos = atomicAdd(&cur[rr >> LOG_NPB], 1u);
            payload[pos] = ((rr & (NPB - 1)) << 21) | (unsigned)c.y;
        }
        {
            const unsigned rr = (unsigned)r.z;
            const unsigned pos = atomicAdd(&cur[rr >> LOG_NPB], 1u);
            payload[pos] = ((rr & (NPB - 1)) << 21) | (unsigned)c.z;
        }
        {
            const unsigned rr = (unsigned)r.w;
            const unsigned pos = atomicAdd(&cur[rr >> LOG_NPB], 1u);
            payload[pos] = ((rr & (NPB - 1)) << 21) | (unsigned)c.w;
        }
    }
    for (int e = (nv << 2) + blockIdx.x * 256 + threadIdx.x; e < E; e += T) {
        const unsigned rr = (unsigned)row[e];
        const unsigned pos = atomicAdd(&cur[rr >> LOG_NPB], 1u);
        payload[pos] = ((rr & (NPB - 1)) << 21) | (unsigned)col[e];
    }
}

// ---------------- K4: per-bucket LDS accumulate + node epilogue ------------
// 512 threads (8 waves), 20KB LDS -> 4 blocks/CU = 32 waves/CU.
__global__ void __launch_bounds__(512, 8) bucket_reduce_kernel(
        const float2* __restrict__ x,
        const float* __restrict__ W1,   // [2][16]
        const float* __restrict__ b1,   // [16]
        const float* __restrict__ W2,   // [16]
        const unsigned* __restrict__ base,
        const unsigned* __restrict__ payload,
        const int* __restrict__ depth,
        const float* __restrict__ depth_scale,
        const float* __restrict__ depth_theta,
        const float* __restrict__ eta_p,
        float2* __restrict__ out, int V) {
    __shared__ float  sden[NPB];
    __shared__ float  smx[NPB];
    __shared__ float  smy[NPB];
    __shared__ float2 sxi[NPB];
    const int b = blockIdx.x;
    const int nodeBase = b << LOG_NPB;
    for (int i = threadIdx.x; i < NPB; i += 512) {
        sden[i] = 0.f; smx[i] = 0.f; smy[i] = 0.f;
        sxi[i] = x[nodeBase + i];          // coalesced stage; row endpoints
    }
    __syncthreads();

    const unsigned e0 = base[b], e1 = base[b + 1];
    for (unsigned e = e0 + threadIdx.x; e < e1; e += 512) {
        const unsigned p = payload[e];
        const unsigned lrow = p >> 21;
        const unsigned c = p & 0x1FFFFFu;
        const float2 xi = sxi[lrow];                 // LDS, immune to L1 thrash
        const float2 xj = x[c];                      // random gather, L2/LLC

        // sub = mobius_add(-xi, xj), curvature 1
        const float ax = -xi.x, ay = -xi.y;
        const float bx = xj.x,  by = xj.y;
        const float a2 = ax * ax + ay * ay;
        const float b2 = bx * bx + by * by;
        const float ab = ax * bx + ay * by;
        const float ca = 1.0f + 2.0f * ab + b2;
        const float cb = 1.0f - a2;
        const float dn = fmaxf(1.0f + 2.0f * ab + a2 * b2, EPSF);
        const float rdn = __fdividef(1.0f, dn);
        const float subx = (ca * ax + cb * bx) * rdn;
        const float suby = (ca * ay + cb * by) * rdn;

        // log map
        const float n = fmaxf(sqrtf(subx * subx + suby * suby), EPSF);
        const float M = fmaxf(1.0f - (xi.x * xi.x + xi.y * xi.y), EPSF);
        const float scl = M * fast_atanh(fminf(n, MAX_ATANH)) * __fdividef(1.0f, n);
        const float vx = scl * subx;
        const float vy = scl * suby;

        // MLP scorer: gelu(v @ W1 + b1) @ W2  (exact GELU via fast erf)
        float s = 0.0f;
        #pragma unroll
        for (int k = 0; k < ATT; ++k) {
            const float u = fmaf(vx, W1[k], fmaf(vy, W1[ATT + k], b1[k]));
            s = fmaf(fast_gelu(u), W2[k], s);
        }

        // max-free softmax numerator (f32 exp range is ample here)
        const float ee = __expf(s);
        atomicAdd(&sden[lrow], ee);        // ds_add_f32 — LDS, cheap
        atomicAdd(&smx[lrow], ee * vx);
        atomicAdd(&smy[lrow], ee * vy);
    }
    __syncthreads();

    // node epilogue: normalize, depth mixer, exp-map
    const float eta = eta_p[0];
    for (int i = threadIdx.x; i < NPB; i += 512) {
        const int v = nodeBase + i;
        if (v >= V) break;
        const float rdv = __fdividef(1.0f, fmaxf(sden[i], EPSF));
        const float mx = smx[i] * rdv;
        const float my = smy[i] * rdv;

        const int d = min(depth[v], 511);
        const float k   = depth_scale[d];
        const float ang = depth_theta[d];
        const float cs = __cosf(ang), sn = __sinf(ang);
        const float m0 = eta * (k * (cs * mx - sn * my));
        const float m1 = eta * (k * (sn * mx + cs * my));

        const float2 xi = sxi[i];

        const float n = fmaxf(sqrtf(m0 * m0 + m1 * m1), EPSF);
        const float M = fmaxf(1.0f - (xi.x * xi.x + xi.y * xi.y), EPSF);
        const float t = fast_tanh(__fdividef(n, M));
        const float tn = t * __fdividef(1.0f, n);
        const float bx = tn * m0;
        const float by = tn * m1;

        const float a2 = xi.x * xi.x + xi.y * xi.y;
        const float b2 = bx * bx + by * by;
        const float ab = xi.x * bx + xi.y * by;
        const float ca = 1.0f + 2.0f * ab + b2;
        const float cb = 1.0f - a2;
        const float dn = fmaxf(1.0f + 2.0f * ab + a2 * b2, EPSF);
        const float rdn = __fdividef(1.0f, dn);

        out[v] = make_float2((ca * xi.x + cb * bx) * rdn,
                             (ca * xi.y + cb * by) * rdn);
    }
}

extern "C" void kernel_launch(void* const* d_in, const int* in_sizes, int n_in,
                              void* d_out, int out_size, void* d_ws, size_t ws_size,
                              hipStream_t stream) {
    const float2* x          = (const float2*)d_in[0];
    const float*  W1         = (const float*)d_in[1];
    const float*  b1         = (const float*)d_in[2];
    const float*  W2         = (const float*)d_in[3];
    const float*  eta        = (const float*)d_in[4];
    const float*  dscale     = (const float*)d_in[5];
    const float*  dtheta     = (const float*)d_in[6];
    const int*    edge_index = (const int*)d_in[7];
    const int*    depth      = (const int*)d_in[8];

    const int V = in_sizes[0] / 2;
    const int E = in_sizes[7] / 2;
    const int B = (V + NPB - 1) >> LOG_NPB;       // 2048 for V = 2^21

    const int* row = edge_index;
    const int* col = edge_index + E;

    // workspace layout (all u32): payload[E] | counts[B*NBLK] | within[B*NBLK]
    //                             | totals[B] | base[B+1]
    unsigned* payload = (unsigned*)d_ws;
    unsigned* counts  = payload + E;
    unsigned* within  = counts + (size_t)B * NBLK;
    unsigned* totals  = within + (size_t)B * NBLK;
    unsigned* base    = totals + B;

    hist_kernel<<<NBLK, 256, 0, stream>>>(row, E, B, counts);
    scan_blocks_kernel<<<B, 256, 0, stream>>>(counts, within, totals);
    scan_totals_kernel<<<1, 256, 0, stream>>>(totals, base, B);
    scatter_kernel<<<NBLK, 256, 0, stream>>>(row, col, E, B, base, within, payload);
    bucket_reduce_kernel<<<B, 512, 0, stream>>>(x, W1, b1, W2, base, payload,
                                                depth, dscale, dtheta, eta,
                                                (float2*)d_out, V);
}